// Round 4
// baseline (729.801 us; speedup 1.0000x reference)
//
#include <hip/hip_runtime.h>
#include <cstdint>

// ---------------- constants ----------------
#define DM    1024
#define NHEAD 16
#define FFDIM 4096
#define MROWS 16384   // B*N = 8*2048
#define QKVS  3072

static constexpr float LAMBDA_INIT_F = 0.3555090675909693f;   // 0.8 - 0.6*exp(-0.3)
static constexpr float ONE_MINUS_LI  = 1.0f - 0.3555090675909693f;
static constexpr float QSCALE        = 0.17677669529663687f;  // 32^-0.5

typedef __attribute__((ext_vector_type(8))) short bf16x8;   // 8 bf16 in 4 VGPRs
typedef __attribute__((ext_vector_type(4))) float f32x4;

__device__ __forceinline__ unsigned short f2bf(float f) {
    union { float f; unsigned int i; } w; w.f = f;
    unsigned int x = w.i;
    return (unsigned short)((x + 0x7fffu + ((x >> 16) & 1u)) >> 16);  // RNE
}
__device__ __forceinline__ float bf2f(unsigned short u) {
    union { unsigned int i; float f; } w; w.i = ((unsigned int)u) << 16; return w.f;
}

// async global(16B/lane) -> LDS(wave-uniform base + lane*16B)
__device__ __forceinline__ void load_lds16(const void* gptr, void* lptr) {
    __builtin_amdgcn_global_load_lds(
        (const __attribute__((address_space(1))) unsigned int*)gptr,
        (__attribute__((address_space(3))) unsigned int*)lptr, 16, 0, 0);
}

// ---------------- fused f32 -> bf16 weight conversion ------------------------
__global__ __launch_bounds__(256) void cvt6_kernel(const float* __restrict__ Wq,
                                                   const float* __restrict__ Wk,
                                                   const float* __restrict__ Wv,
                                                   const float* __restrict__ Wo,
                                                   const float* __restrict__ W1,
                                                   const float* __restrict__ W2,
                                                   unsigned short* __restrict__ wqkv,
                                                   unsigned short* __restrict__ wo,
                                                   unsigned short* __restrict__ w1,
                                                   unsigned short* __restrict__ w2)
{
    const int b = blockIdx.x;
    const float* src;
    unsigned short* dst;
    int off;
    if (b < 3072)      { src = (b < 1024) ? Wq : (b < 2048) ? Wk : Wv;
                         dst = wqkv + (b >> 10) * (DM * DM);
                         off = (b & 1023) * 1024; }
    else if (b < 4096) { src = Wo; dst = wo; off = (b - 3072) * 1024; }
    else if (b < 8192) { src = W1; dst = w1; off = (b - 4096) * 1024; }
    else               { src = W2; dst = w2; off = (b - 8192) * 1024; }
    const int i = off + threadIdx.x * 4;
    const float4 v = *(const float4*)&src[i];
    ushort4 o;
    o.x = f2bf(v.x); o.y = f2bf(v.y); o.z = f2bf(v.z); o.w = f2bf(v.w);
    *(ushort4*)&dst[i] = o;
}

// ---------------- LayerNorm (f32 in, bf16 out): one block / row of 1024 ------
__global__ __launch_bounds__(256) void ln_kernel(const float* __restrict__ xin,
                                                 const float* __restrict__ g,
                                                 const float* __restrict__ b,
                                                 unsigned short* __restrict__ out)
{
    const int row = blockIdx.x;
    const int tid = threadIdx.x;
    const float* xr = xin + (size_t)row * DM;
    float v[4];
    #pragma unroll
    for (int i = 0; i < 4; ++i) v[i] = xr[tid + 256 * i];
    float s1 = v[0] + v[1] + v[2] + v[3];
    float s2 = v[0]*v[0] + v[1]*v[1] + v[2]*v[2] + v[3]*v[3];
    #pragma unroll
    for (int off = 32; off > 0; off >>= 1) {
        s1 += __shfl_down(s1, off);
        s2 += __shfl_down(s2, off);
    }
    __shared__ float red[8];
    const int wv = tid >> 6;
    if ((tid & 63) == 0) { red[wv] = s1; red[4 + wv] = s2; }
    __syncthreads();
    s1 = red[0] + red[1] + red[2] + red[3];
    s2 = red[4] + red[5] + red[6] + red[7];
    const float mean = s1 * (1.0f / DM);
    const float var  = s2 * (1.0f / DM) - mean * mean;
    const float inv  = rsqrtf(var + 1e-5f);
    #pragma unroll
    for (int i = 0; i < 4; ++i) {
        const int c = tid + 256 * i;
        out[(size_t)row * DM + c] = f2bf((v[i] - mean) * inv * g[c] + b[c]);
    }
}

// ---------------- bf16 MFMA GEMM: 256x256 tile, BK=64, prefetched phases -----
// C = A[M,K](lda=K) * W[N,K]^T(ldb) (+epilogue).
// 8 waves (2 row-groups x 4 col-groups), per-wave output 128x64 interleaved.
// LDS: A[2][256][64] + B[2][256][64] bf16 = 128 KiB, double-buffered by K-tile.
// Swizzle: element (row, colgrp g of 8) lives at LDS colgrp g^(row&7), produced
// by pre-swizzling the global source column per staging lane. 0 bank conflicts.
//
// Gray-code phase walk with one-phase-ahead fragment prefetch: each phase's
// MFMAs consume ONLY fragments read in an earlier phase, so they never stall
// on lgkm; the current phase's ds_reads execute on the LDS pipe UNDER the
// MFMA burst (round-2 post-mortem: per-phase read-burst/MFMA-burst lockstep
// serialization was ~5120 cyc/tile vs 2048 MFMA floor).
//   p0: MFMA a(h0)xb0 -> acc[0..3][0,1]; early-read b1(t);          stage A0(t+2)
//   p1: MFMA a(h0)xb1 -> acc[0..3][2,3]; late-read  a(h1,t);        stage B0(t+2)
//   p2: MFMA a(h1)xb1 -> acc[4..7][2,3]; (no reads)                 stage A1(t+2); vmcnt
//   p3: MFMA a(h1)xb0 -> acc[4..7][0,1]; late-read a(h0,t+1)+b0(t+1) stage B1(t+2)
// "late" reads overwrite the registers that phase's MFMAs just consumed
// (in-order issue makes the reg-WAR safe); sched_barrier(0) pins them after
// the MFMA cluster so the scheduler can't rename-hoist (VGPR control).
// s_waitcnt lgkmcnt(0) before EVERY barrier: prefetched reads are consumed
// AFTER a barrier, so the barrier alone no longer proves a slot's readers are
// done before a staging overwrite; the lgkm drain restores the proof (and is
// free: the reads complete under the MFMA burst).
// ROUND-3 BUG (fixed): the PROLOGUE fragment reads of A0/B0(buf0) had no
// lgkm-drain+barrier before p0(t=0)'s STG_A overwrite of slot A0(buf0) -- a
// fast wave's stage data could land before a slow wave's prologue ds_read
// executed (absmax 0.47). Fix: lgkmcnt(0)+s_barrier after prologue reads.
// vmcnt: stages issue in order A0,B0,A1,B1 of t+2 at p0..p3. At end-p2(t),
// outstanding = {B1(t+1), A0,B0,A1(t+2)} = 8 loads; vmcnt(6) drains B1(t+1)
// and all older => ALL of tile t+1 resident before p3(t)'s t+1-fragment reads
// and p0/p1(t+1). When t+2 >= KT use vmcnt(0) (stages stop, count shrinks).
// XCD swizzle (T1): same-XCD blocks cover a contiguous grid chunk (L2 reuse).
// EPI 0: plain -> bf16 | 1: +bias+resid -> f32 | 2: +bias,relu -> bf16
// EPI 4: +resid -> f32 (K-split accumulate, resid may alias Cout elementwise)
template<int EPI>
__global__ __launch_bounds__(512, 2) void gemm256(const unsigned short* __restrict__ A,
                                                  const unsigned short* __restrict__ W,
                                                  void* __restrict__ Cout,
                                                  const float* __restrict__ bias,
                                                  const float* __restrict__ resid,
                                                  int M, int N, int K, int ldb)
{
    __shared__ __align__(16) unsigned short Al[2][256][64];   // 64 KB
    __shared__ __align__(16) unsigned short Bl[2][256][64];   // 64 KB

    const int tid  = threadIdx.x;
    const int lane = tid & 63;
    const int wv   = tid >> 6;
    const int l15  = lane & 15;
    const int q4   = lane >> 4;
    const int wg   = wv >> 2;       // 0..1 row group
    const int cg   = wv & 3;        // 0..3 col group

    // ---- XCD-aware block swizzle (all grids here have nwg % 8 == 0)
    int bx = blockIdx.x, by = blockIdx.y;
    {
        const int gx  = gridDim.x;
        const int nwg = gx * gridDim.y;
        if ((nwg & 7) == 0) {
            const int lin = by * gx + bx;
            const int swz = (lin & 7) * (nwg >> 3) + (lin >> 3);
            bx = swz % gx;
            by = swz / gx;
        }
    }
    const int m0 = by * 256;
    const int n0 = bx * 256;
    const int KT = K >> 6;          // K-tiles of 64

    // ---- staging (write) addressing: lane row sr=tid/8, pre-swizzled colgrp
    const int sr = tid >> 3;                      // 0..63
    const int sc = (tid & 7) ^ (sr & 7);
    const unsigned short* gA = A + (size_t)(m0 + sr) * K   + sc * 8;
    const unsigned short* gB = W + (size_t)(n0 + sr) * ldb + sc * 8;
    const size_t aH = (size_t)128 * K;            // global half-tile row offset
    const size_t bH = (size_t)128 * ldb;
    const size_t aC = (size_t)64 * K;             // chunk (second 64 rows)
    const size_t bC = (size_t)64 * ldb;
    unsigned short* lA = &Al[0][0][0] + wv * 512; // wave-uniform: rows 8w..8w+7
    unsigned short* lB = &Bl[0][0][0] + wv * 512;

#define STG_A(boff, hoff, gp) do { \
    load_lds16((gp),      lA + (boff) + (hoff)); \
    load_lds16((gp) + aC, lA + (boff) + (hoff) + 4096); } while (0)
#define STG_B(boff, hoff, gp) do { \
    load_lds16((gp),      lB + (boff) + (hoff)); \
    load_lds16((gp) + bC, lB + (boff) + (hoff) + 4096); } while (0)

    // ---- prologue: tile0 full + tile1 full (16 loads/thread)
    STG_A(0, 0,    gA);
    STG_B(0, 0,    gB);
    STG_A(0, 8192, gA + aH);
    STG_B(0, 8192, gB + bH);
    if (KT > 1) {
        STG_A(16384, 0,    gA + 64);
        STG_B(16384, 0,    gB + 64);
        STG_A(16384, 8192, gA + aH + 64);
        STG_B(16384, 8192, gB + bH + 64);
        asm volatile("s_waitcnt vmcnt(8)" ::: "memory");   // tile0 landed
    } else {
        asm volatile("s_waitcnt vmcnt(0)" ::: "memory");
    }
    __builtin_amdgcn_s_barrier();
    __builtin_amdgcn_sched_barrier(0);

    // ---- fragment-read addressing (swizzled col-groups)
    const int so0 = ( q4      ^ (l15 & 7)) * 8;   // kk=0
    const int so1 = ((q4 + 4) ^ (l15 & 7)) * 8;   // kk=1
    const unsigned short* rA = &Al[0][wg * 64 + l15][0];
    const unsigned short* rB = &Bl[0][cg * 32 + l15][0];

    const f32x4 fz = {0.f, 0.f, 0.f, 0.f};
    f32x4 acc[8][4];
    #pragma unroll
    for (int i = 0; i < 8; ++i)
        #pragma unroll
        for (int j = 0; j < 4; ++j) acc[i][j] = fz;

    bf16x8 af[4][2], b0f[2][2], b1f[2][2];

    // prologue fragment reads: a(h0) and b0 of tile 0
    #pragma unroll
    for (int mf = 0; mf < 4; ++mf) {
        af[mf][0] = *(const bf16x8*)&rA[mf * 1024 + so0];
        af[mf][1] = *(const bf16x8*)&rA[mf * 1024 + so1];
    }
    #pragma unroll
    for (int nf = 0; nf < 2; ++nf) {
        b0f[nf][0] = *(const bf16x8*)&rB[nf * 1024 + so0];
        b0f[nf][1] = *(const bf16x8*)&rB[nf * 1024 + so1];
    }
    // RACE FIX: all waves' prologue reads of A0/B0(buf0) must complete before
    // p0(t=0) overwrites slot A0(buf0) with tile-2 data.
    asm volatile("s_waitcnt lgkmcnt(0)" ::: "memory");
    __builtin_amdgcn_sched_barrier(0);
    __builtin_amdgcn_s_barrier();
    __builtin_amdgcn_sched_barrier(0);

    for (int t = 0; t < KT; ++t) {
        const int bo = (t & 1) << 14;   // current LDS buffer (element offset)
        const int bn = bo ^ 16384;      // next buffer
        const int k2 = (t + 2) << 6;    // global col offset of tile t+2

        // ===== p0: MFMA a(h0) x b0; early-read b1(t); stage A0(t+2) =====
        b1f[0][0] = *(const bf16x8*)&rB[bo + 8192 + 0 * 1024 + so0];
        b1f[0][1] = *(const bf16x8*)&rB[bo + 8192 + 0 * 1024 + so1];
        b1f[1][0] = *(const bf16x8*)&rB[bo + 8192 + 1 * 1024 + so0];
        b1f[1][1] = *(const bf16x8*)&rB[bo + 8192 + 1 * 1024 + so1];
        if (t + 2 < KT) STG_A(bo, 0, gA + k2);
        __builtin_amdgcn_sched_barrier(0);
        __builtin_amdgcn_s_setprio(1);
        #pragma unroll
        for (int mf = 0; mf < 4; ++mf)
            #pragma unroll
            for (int nf = 0; nf < 2; ++nf) {
                acc[mf][nf] = __builtin_amdgcn_mfma_f32_16x16x32_bf16(af[mf][0], b0f[nf][0], acc[mf][nf], 0, 0, 0);
                acc[mf][nf] = __builtin_amdgcn_mfma_f32_16x16x32_bf16(af[mf][1], b0f[nf][1], acc[mf][nf], 0, 0, 0);
            }
        __builtin_amdgcn_s_setprio(0);
        asm volatile("s_waitcnt lgkmcnt(0)" ::: "memory");
        __builtin_amdgcn_sched_barrier(0);
        __builtin_amdgcn_s_barrier();
        __builtin_amdgcn_sched_barrier(0);

        // ===== p1: MFMA a(h0) x b1; late-read a(h1,t); stage B0(t+2) =====
        if (t + 2 < KT) STG_B(bo, 0, gB + k2);
        __builtin_amdgcn_s_setprio(1);
        #pragma unroll
        for (int mf = 0; mf < 4; ++mf)
            #pragma unroll
            for (int nf = 0; nf < 2; ++nf) {
                acc[mf][2 + nf] = __builtin_amdgcn_mfma_f32_16x16x32_bf16(af[mf][0], b1f[nf][0], acc[mf][2 + nf], 0, 0, 0);
                acc[mf][2 + nf] = __builtin_amdgcn_mfma_f32_16x16x32_bf16(af[mf][1], b1f[nf][1], acc[mf][2 + nf], 0, 0, 0);
            }
        __builtin_amdgcn_s_setprio(0);
        __builtin_amdgcn_sched_barrier(0);
        #pragma unroll
        for (int mf = 0; mf < 4; ++mf) {
            af[mf][0] = *(const bf16x8*)&rA[bo + 8192 + mf * 1024 + so0];
            af[mf][1] = *(const bf16x8*)&rA[bo + 8192 + mf * 1024 + so1];
        }
        asm volatile("s_waitcnt lgkmcnt(0)" ::: "memory");
        __builtin_amdgcn_sched_barrier(0);
        __builtin_amdgcn_s_barrier();
        __builtin_amdgcn_sched_barrier(0);

        // ===== p2: MFMA a(h1) x b1; no reads; stage A1(t+2); vmcnt =====
        if (t + 2 < KT) STG_A(bo, 8192, gA + aH + k2);
        __builtin_amdgcn_s_setprio(1);
        #pragma unroll
        for (int mf = 0; mf < 4; ++mf)
            #pragma unroll
            for (int nf = 0; nf < 2; ++nf) {
                acc[4 + mf][2 + nf] = __builtin_amdgcn_mfma_f32_16x16x32_bf16(af[mf][0], b1f[nf][0], acc[4 + mf][2 + nf], 0, 0, 0);
                acc[4 + mf][2 + nf] = __builtin_amdgcn_mfma_f32_16x16x32_bf16(af[mf][1], b1f[nf][1], acc[4 + mf][2 + nf], 0, 0, 0);
            }
        __builtin_amdgcn_s_setprio(0);
        if (t + 2 < KT) {
            asm volatile("s_waitcnt vmcnt(6)" ::: "memory");   // tile t+1 fully landed
        } else {
            asm volatile("s_waitcnt vmcnt(0)" ::: "memory");
        }
        __builtin_amdgcn_sched_barrier(0);
        __builtin_amdgcn_s_barrier();
        __builtin_amdgcn_sched_barrier(0);

        // ===== p3: MFMA a(h1) x b0; late-read a(h0,t+1)+b0(t+1); stage B1(t+2)
        if (t + 2 < KT) STG_B(bo, 8192, gB + bH + k2);
        __builtin_amdgcn_s_setprio(1);
        #pragma unroll
        for (int mf = 0; mf < 4; ++mf)
            #pragma unroll
            for (int nf = 0; nf < 2; ++nf) {
                acc[4 + mf][nf] = __builtin_amdgcn_mfma_f32_16x16x32_bf16(af[mf][0], b0f[nf][0], acc[4 + mf][nf], 0, 0, 0);
                acc[4 + mf][nf] = __builtin_amdgcn_mfma_f32_16x16x32_bf16(af[mf][1], b0f[nf][1], acc[4 + mf][nf], 0, 0, 0);
            }
        __builtin_amdgcn_s_setprio(0);
        __builtin_amdgcn_sched_barrier(0);
        if (t + 1 < KT) {
            #pragma unroll
            for (int mf = 0; mf < 4; ++mf) {
                af[mf][0] = *(const bf16x8*)&rA[bn + mf * 1024 + so0];
                af[mf][1] = *(const bf16x8*)&rA[bn + mf * 1024 + so1];
            }
            #pragma unroll
            for (int nf = 0; nf < 2; ++nf) {
                b0f[nf][0] = *(const bf16x8*)&rB[bn + nf * 1024 + so0];
                b0f[nf][1] = *(const bf16x8*)&rB[bn + nf * 1024 + so1];
            }
            asm volatile("s_waitcnt lgkmcnt(0)" ::: "memory");
            __builtin_amdgcn_sched_barrier(0);
            __builtin_amdgcn_s_barrier();
            __builtin_amdgcn_sched_barrier(0);
        }
    }
#undef STG_A
#undef STG_B

    // ---- epilogue: D element (row q4*4+rr, col l15) per 16x16 subtile ----
    #pragma unroll
    for (int hm = 0; hm < 2; ++hm)
    #pragma unroll
    for (int mf = 0; mf < 4; ++mf)
    #pragma unroll
    for (int hb = 0; hb < 2; ++hb)
    #pragma unroll
    for (int nf = 0; nf < 2; ++nf)
    #pragma unroll
    for (int rr = 0; rr < 4; ++rr) {
        const int m = m0 + hm * 128 + wg * 64 + mf * 16 + q4 * 4 + rr;
        const int n = n0 + hb * 128 + cg * 32 + nf * 16 + l15;
        const size_t off = (size_t)m * N + n;
        float c = acc[hm * 4 + mf][hb * 2 + nf][rr];
        if (EPI == 0) {
            ((unsigned short*)Cout)[off] = f2bf(c);
        } else if (EPI == 1) {
            ((float*)Cout)[off] = c + bias[n] + resid[off];
        } else if (EPI == 2) {
            ((unsigned short*)Cout)[off] = f2bf(fmaxf(c + bias[n], 0.f));
        } else {   // EPI == 4: K-split accumulate
            ((float*)Cout)[off] = c + resid[off];
        }
    }
}

// ---------------- per-position differential attention: 1 wave / token --------
__global__ __launch_bounds__(256) void attn_pos(const unsigned short* __restrict__ qkv,
                                                const float* __restrict__ lq1,
                                                const float* __restrict__ lq2,
                                                const float* __restrict__ lk1,
                                                const float* __restrict__ lk2,
                                                unsigned short* __restrict__ outg)
{
    __shared__ __align__(16) float q2[4][32][36];
    __shared__ __align__(16) float k2[4][32][36];
    __shared__ __align__(16) float v2[4][16][64];
    __shared__ float att2[4][16][17];

    const int tid  = threadIdx.x;
    const int wave = tid >> 6;
    const int lane = tid & 63;
    const int pos  = blockIdx.x * 4 + wave;

    float s1 = 0.f, s2 = 0.f;
    #pragma unroll
    for (int i = 0; i < 32; ++i) {
        s1 += lq1[i] * lk1[i];
        s2 += lq2[i] * lk2[i];
    }
    const float lam = __expf(s1) - __expf(s2) + LAMBDA_INIT_F;

    const unsigned short* qrow = qkv + (size_t)pos * QKVS;
    const unsigned short* krow = qrow + DM;
    const unsigned short* vrow = qrow + 2 * DM;

    unsigned short tq[16], tk[16], tv[16];
    *(uint4*)&tq[0] = *(const uint4*)&qrow[lane * 16];
    *(uint4*)&tq[8] = *(const uint4*)&qrow[lane * 16 + 8];
    *(uint4*)&tk[0] = *(const uint4*)&krow[lane * 16];
    *(uint4*)&tk[8] = *(const uint4*)&krow[lane * 16 + 8];
    *(uint4*)&tv[0] = *(const uint4*)&vrow[lane * 16];
    *(uint4*)&tv[8] = *(const uint4*)&vrow[lane * 16 + 8];

    #pragma unroll
    for (int jj = 0; jj < 16; ++jj) {
        const int c  = lane * 16 + jj;
        const int h  = c >> 6;
        const int d  = (c >> 1) & 31;
        const int qi = c & 1;
        q2[wave][qi * 16 + h][d] = bf2f(tq[jj]) * QSCALE;
        k2[wave][qi * 16 + h][d] = bf2f(tk[jj]);
        v2[wave][c >> 6][c & 63] = bf2f(tv[jj]);
    }
    __syncthreads();

    const int qh = lane & 31, half = lane >> 5;
    float qreg[32];
    #pragma unroll
    for (int d4 = 0; d4 < 32; d4 += 4) {
        const f32x4 t = *(const f32x4*)&q2[wave][qh][d4];
        qreg[d4] = t[0]; qreg[d4+1] = t[1]; qreg[d4+2] = t[2]; qreg[d4+3] = t[3];
    }
    float p[16];
    #pragma unroll
    for (int jj = 0; jj < 16; ++jj) {
        const float* kr = &k2[wave][half * 16 + jj][0];
        float a = 0.f;
        #pragma unroll
        for (int d4 = 0; d4 < 32; d4 += 4) {
            const f32x4 kv = *(const f32x4*)&kr[d4];
            a += qreg[d4]*kv[0] + qreg[d4+1]*kv[1] + qreg[d4+2]*kv[2] + qreg[d4+3]*kv[3];
        }
        p[jj] = a;
    }

    float mx = p[0];
    #pragma unroll
    for (int jj = 1; jj < 16; ++jj) mx = fmaxf(mx, p[jj]);
    mx = fmaxf(mx, __shfl_xor(mx, 32));
    float sum = 0.f;
    #pragma unroll
    for (int jj = 0; jj < 16; ++jj) { p[jj] = __expf(p[jj] - mx); sum += p[jj]; }
    sum += __shfl_xor(sum, 32);
    const float inv = 1.0f / sum;

    if (half == 0 && qh < 16) {
        #pragma unroll
        for (int jj = 0; jj < 16; ++jj) att2[wave][qh][jj] = p[jj] * inv;
    }
    __syncthreads();
    if (half == 1 && qh >= 16) {
        const int a = qh - 16;
        #pragma unroll
        for (int jj = 0; jj < 16; ++jj) att2[wave][a][jj] -= lam * p[jj] * inv;
    }
    __syncthreads();

    const int a   = lane & 15;
    const int ddb = (lane >> 4) * 16;
    float areg[16];
    #pragma unroll
    for (int h = 0; h < 16; ++h) areg[h] = att2[wave][a][h];
    float o[16];
    #pragma unroll
    for (int j = 0; j < 16; ++j) o[j] = 0.f;
    #pragma unroll
    for (int h = 0; h < 16; ++h) {
        #pragma unroll
        for (int j4 = 0; j4 < 16; j4 += 4) {
            const f32x4 vv = *(const f32x4*)&v2[wave][h][ddb + j4];
            o[j4]   += areg[h] * vv[0];
            o[j4+1] += areg[h] * vv[1];
            o[j4+2] += areg[h] * vv[2];
            o[j4+3] += areg[h] * vv[3];
        }
    }

    float ss = 0.f;
    #pragma unroll
    for (int j = 0; j < 16; ++j) ss += o[j] * o[j];
    ss += __shfl_xor(ss, 16);
    ss += __shfl_xor(ss, 32);
    const float scl = rsqrtf(ss * (1.0f / 64.0f) + 1e-5f) * ONE_MINUS_LI;

    unsigned short ob[16];
    #pragma unroll
    for (int j = 0; j < 16; ++j) ob[j] = f2bf(o[j] * scl);
    unsigned short* orow = outg + (size_t)pos * DM + a * 64 + ddb;
    *(uint4*)&orow[0] = *(const uint4*)&ob[0];
    *(uint4*)&orow[8] = *(const uint4*)&ob[8];
}

// ---------------- launcher ----------------
extern "C" void kernel_launch(void* const* d_in, const int* in_sizes, int n_in,
                              void* d_out, int out_size, void* d_ws, size_t ws_size,
                              hipStream_t stream)
{
    const float* x   = (const float*)d_in[0];
    const float* Wq  = (const float*)d_in[1];
    const float* Wk  = (const float*)d_in[2];
    const float* Wv  = (const float*)d_in[3];
    const float* lq1 = (const float*)d_in[4];
    const float* lq2 = (const float*)d_in[5];
    const float* lk1 = (const float*)d_in[6];
    const float* lk2 = (const float*)d_in[7];
    const float* Wo  = (const float*)d_in[8];
    const float* bo  = (const float*)d_in[9];
    const float* g1  = (const float*)d_in[10];
    const float* be1 = (const float*)d_in[11];
    const float* g2  = (const float*)d_in[12];
    const float* be2 = (const float*)d_in[13];
    const float* W1  = (const float*)d_in[14];
    const float* b1  = (const float*)d_in[15];
    const float* W2  = (const float*)d_in[16];
    const float* b2  = (const float*)d_in[17];
    (void)in_sizes; (void)n_in; (void)out_size;

    const size_t MB = 1ull << 20;
    char* ws = (char*)d_ws;
    unsigned short* wqkv = (unsigned short*)(ws);             //  6 MB  [3072][1024] bf16
    unsigned short* wo   = (unsigned short*)(ws + 6 * MB);    //  2 MB
    unsigned short* w1   = (unsigned short*)(ws + 8 * MB);    //  8 MB
    unsigned short* w2   = (unsigned short*)(ws + 16 * MB);   //  8 MB
    unsigned short* h    = (unsigned short*)(ws + 24 * MB);   // 32 MB bf16, reused as attn-out
    unsigned short* qkv  = (unsigned short*)(ws + 56 * MB);   // 96 MB bf16 [16384][3072]
    float*          conn = (float*)(ws + 56 * MB);            // 64 MB f32 (over qkv, dead)
    unsigned short* attn = h;                                 // over h (dead)
    unsigned short* h2   = (unsigned short*)(ws + 120 * MB);  // 32 MB (over qkv tail, dead)
    unsigned short* t    = (unsigned short*)(ws + 152 * MB);  // FFN intermediate (FF-chunked)

    // chunk FFN over the FF dimension so every GEMM keeps >=256 blocks
    int nf = 1;
    while (nf < 16 && 152 * MB + (size_t)MROWS * (FFDIM / nf) * 2 > ws_size) nf <<= 1;
    const int FC = FFDIM / nf;

    const dim3 b256(256), b512(512);

    cvt6_kernel<<<12288, b256, 0, stream>>>(Wq, Wk, Wv, Wo, W1, W2, wqkv, wo, w1, w2);

    ln_kernel<<<MROWS, b256, 0, stream>>>(x, g1, be1, h);

    gemm256<0><<<dim3(QKVS / 256, MROWS / 256), b512, 0, stream>>>(
        h, wqkv, qkv, nullptr, nullptr, MROWS, QKVS, DM, DM);

    attn_pos<<<MROWS / 4, b256, 0, stream>>>(qkv, lq1, lq2, lk1, lk2, attn);

    gemm256<1><<<dim3(DM / 256, MROWS / 256), b512, 0, stream>>>(
        attn, wo, conn, bo, x, MROWS, DM, DM, DM);

    ln_kernel<<<MROWS, b256, 0, stream>>>(conn, g2, be2, h2);

    for (int c = 0; c < nf; ++c) {
        // t[M][FC] = relu(h2 @ W1[c*FC:(c+1)*FC, :]^T + b1[c*FC:])
        gemm256<2><<<dim3(FC / 256, MROWS / 256), b512, 0, stream>>>(
            h2, w1 + (size_t)c * FC * DM, t, b1 + c * FC, nullptr, MROWS, FC, DM, DM);
        // d_out (+)= t @ W2[:, c*FC:(c+1)*FC]^T [+ b2 + conn on first chunk]
        if (c == 0)
            gemm256<1><<<dim3(DM / 256, MROWS / 256), b512, 0, stream>>>(
                t, w2 + (size_t)c * FC, (float*)d_out, b2, conn, MROWS, DM, FC, FFDIM);
        else
            gemm256<4><<<dim3(DM / 256, MROWS / 256), b512, 0, stream>>>(
                t, w2 + (size_t)c * FC, (float*)d_out, nullptr, (const float*)d_out, MROWS, DM, FC, FFDIM);
    }
}

// Round 6
// 664.978 us; speedup vs baseline: 1.0975x; 1.0975x over previous
//
#include <hip/hip_runtime.h>
#include <cstdint>

// ---------------- constants ----------------
#define DM    1024
#define NHEAD 16
#define FFDIM 4096
#define MROWS 16384   // B*N = 8*2048
#define QKVS  3072

static constexpr float LAMBDA_INIT_F = 0.3555090675909693f;   // 0.8 - 0.6*exp(-0.3)
static constexpr float ONE_MINUS_LI  = 1.0f - 0.3555090675909693f;
static constexpr float QSCALE        = 0.17677669529663687f;  // 32^-0.5

typedef __attribute__((ext_vector_type(8))) short bf16x8;   // 8 bf16 in 4 VGPRs
typedef __attribute__((ext_vector_type(4))) float f32x4;

__device__ __forceinline__ unsigned short f2bf(float f) {
    union { float f; unsigned int i; } w; w.f = f;
    unsigned int x = w.i;
    return (unsigned short)((x + 0x7fffu + ((x >> 16) & 1u)) >> 16);  // RNE
}
__device__ __forceinline__ float bf2f(unsigned short u) {
    union { unsigned int i; float f; } w; w.i = ((unsigned int)u) << 16; return w.f;
}

// async global(16B/lane) -> LDS(wave-uniform base + lane*16B)
__device__ __forceinline__ void load_lds16(const void* gptr, void* lptr) {
    __builtin_amdgcn_global_load_lds(
        (const __attribute__((address_space(1))) unsigned int*)gptr,
        (__attribute__((address_space(3))) unsigned int*)lptr, 16, 0, 0);
}

// ---------------- fused f32 -> bf16 weight conversion ------------------------
__global__ __launch_bounds__(256) void cvt6_kernel(const float* __restrict__ Wq,
                                                   const float* __restrict__ Wk,
                                                   const float* __restrict__ Wv,
                                                   const float* __restrict__ Wo,
                                                   const float* __restrict__ W1,
                                                   const float* __restrict__ W2,
                                                   unsigned short* __restrict__ wqkv,
                                                   unsigned short* __restrict__ wo,
                                                   unsigned short* __restrict__ w1,
                                                   unsigned short* __restrict__ w2)
{
    const int b = blockIdx.x;
    const float* src;
    unsigned short* dst;
    int off;
    if (b < 3072)      { src = (b < 1024) ? Wq : (b < 2048) ? Wk : Wv;
                         dst = wqkv + (b >> 10) * (DM * DM);
                         off = (b & 1023) * 1024; }
    else if (b < 4096) { src = Wo; dst = wo; off = (b - 3072) * 1024; }
    else if (b < 8192) { src = W1; dst = w1; off = (b - 4096) * 1024; }
    else               { src = W2; dst = w2; off = (b - 8192) * 1024; }
    const int i = off + threadIdx.x * 4;
    const float4 v = *(const float4*)&src[i];
    ushort4 o;
    o.x = f2bf(v.x); o.y = f2bf(v.y); o.z = f2bf(v.z); o.w = f2bf(v.w);
    *(ushort4*)&dst[i] = o;
}

// ---------------- LayerNorm (f32 in, bf16 out): one block / row of 1024 ------
// Vectorized (G13): one float4 load per thread (contiguous quads), ushort4 store.
__global__ __launch_bounds__(256) void ln_kernel(const float* __restrict__ xin,
                                                 const float* __restrict__ g,
                                                 const float* __restrict__ b,
                                                 unsigned short* __restrict__ out)
{
    const int row = blockIdx.x;
    const int tid = threadIdx.x;
    const int c0  = tid * 4;
    const float4 v = *(const float4*)&xin[(size_t)row * DM + c0];
    float s1 = v.x + v.y + v.z + v.w;
    float s2 = v.x*v.x + v.y*v.y + v.z*v.z + v.w*v.w;
    #pragma unroll
    for (int off = 32; off > 0; off >>= 1) {
        s1 += __shfl_down(s1, off);
        s2 += __shfl_down(s2, off);
    }
    __shared__ float red[8];
    const int wv = tid >> 6;
    if ((tid & 63) == 0) { red[wv] = s1; red[4 + wv] = s2; }
    __syncthreads();
    s1 = red[0] + red[1] + red[2] + red[3];
    s2 = red[4] + red[5] + red[6] + red[7];
    const float mean = s1 * (1.0f / DM);
    const float var  = s2 * (1.0f / DM) - mean * mean;
    const float inv  = rsqrtf(var + 1e-5f);
    const float4 g4 = *(const float4*)&g[c0];
    const float4 b4 = *(const float4*)&b[c0];
    ushort4 o;
    o.x = f2bf((v.x - mean) * inv * g4.x + b4.x);
    o.y = f2bf((v.y - mean) * inv * g4.y + b4.y);
    o.z = f2bf((v.z - mean) * inv * g4.z + b4.z);
    o.w = f2bf((v.w - mean) * inv * g4.w + b4.w);
    *(ushort4*)&out[(size_t)row * DM + c0] = o;
}

// ---------------- bf16 MFMA GEMM: 256x256 tile, BK=64, 4-phase pipeline ------
// (round-2 schedule: best measured. Rounds 3/4's prefetch variant regressed.)
// C = A[M,K](lda=K) * W[N,K]^T(ldb) (+epilogue).
// 8 waves (2 row-groups x 4 col-groups), per-wave output 128x64 interleaved.
// LDS: A[2][256][64] + B[2][256][64] bf16 = 128 KiB, double-buffered by K-tile.
// Swizzle: element (row, colgrp g of 8) lives at LDS colgrp g^(row&7), produced
// by pre-swizzling the global source column per staging lane. 0 bank conflicts.
// ONE barrier per phase (post-MFMA); reads in first-consumption order so the
// compiler's fine-grained lgkmcnt(N) releases the first MFMA after ~2 reads.
// vmcnt(6) once per tile at p3; XCD swizzle (T1) for L2 reuse.
// EPI 0: plain -> bf16 | 1: +bias+resid -> f32 | 2: +bias,relu -> bf16
// EPI 4: +resid -> f32 (K-split accumulate, resid may alias Cout elementwise)
template<int EPI>
__global__ __launch_bounds__(512, 2) void gemm256(const unsigned short* __restrict__ A,
                                                  const unsigned short* __restrict__ W,
                                                  void* __restrict__ Cout,
                                                  const float* __restrict__ bias,
                                                  const float* __restrict__ resid,
                                                  int M, int N, int K, int ldb)
{
    __shared__ __align__(16) unsigned short Al[2][256][64];   // 64 KB
    __shared__ __align__(16) unsigned short Bl[2][256][64];   // 64 KB

    const int tid  = threadIdx.x;
    const int lane = tid & 63;
    const int wv   = tid >> 6;
    const int l15  = lane & 15;
    const int q4   = lane >> 4;
    const int wg   = wv >> 2;       // 0..1 row group
    const int cg   = wv & 3;        // 0..3 col group

    // ---- XCD-aware block swizzle (all grids here have nwg % 8 == 0)
    int bx = blockIdx.x, by = blockIdx.y;
    {
        const int gx  = gridDim.x;
        const int nwg = gx * gridDim.y;
        if ((nwg & 7) == 0) {
            const int lin = by * gx + bx;
            const int swz = (lin & 7) * (nwg >> 3) + (lin >> 3);
            bx = swz % gx;
            by = swz / gx;
        }
    }
    const int m0 = by * 256;
    const int n0 = bx * 256;
    const int KT = K >> 6;          // K-tiles of 64

    // ---- staging (write) addressing: lane row sr=tid/8, pre-swizzled colgrp
    const int sr = tid >> 3;                      // 0..63
    const int sc = (tid & 7) ^ (sr & 7);
    const unsigned short* gA = A + (size_t)(m0 + sr) * K   + sc * 8;
    const unsigned short* gB = W + (size_t)(n0 + sr) * ldb + sc * 8;
    const size_t aH = (size_t)128 * K;            // global half-tile row offset
    const size_t bH = (size_t)128 * ldb;
    const size_t aC = (size_t)64 * K;             // chunk (second 64 rows)
    const size_t bC = (size_t)64 * ldb;
    unsigned short* lA = &Al[0][0][0] + wv * 512; // wave-uniform: rows 8w..8w+7
    unsigned short* lB = &Bl[0][0][0] + wv * 512;

#define STG_A(boff, hoff, gp) do { \
    load_lds16((gp),      lA + (boff) + (hoff)); \
    load_lds16((gp) + aC, lA + (boff) + (hoff) + 4096); } while (0)
#define STG_B(boff, hoff, gp) do { \
    load_lds16((gp),      lB + (boff) + (hoff)); \
    load_lds16((gp) + bC, lB + (boff) + (hoff) + 4096); } while (0)

    // ---- prologue: tile0 {A0,B0,A1,B1} + tile1 {A0,B0,A1} (7 half-tiles)
    STG_A(0, 0,    gA);
    STG_B(0, 0,    gB);
    STG_A(0, 8192, gA + aH);
    STG_B(0, 8192, gB + bH);
    if (KT > 1) {
        STG_A(16384, 0,    gA + 64);
        STG_B(16384, 0,    gB + 64);
        STG_A(16384, 8192, gA + aH + 64);
        asm volatile("s_waitcnt vmcnt(6)" ::: "memory");   // tile0 landed
    } else {
        asm volatile("s_waitcnt vmcnt(0)" ::: "memory");
    }
    __builtin_amdgcn_s_barrier();
    __builtin_amdgcn_sched_barrier(0);

    // ---- fragment-read addressing (swizzled col-groups)
    const int so0 = ( q4      ^ (l15 & 7)) * 8;   // kk=0
    const int so1 = ((q4 + 4) ^ (l15 & 7)) * 8;   // kk=1
    const unsigned short* rA = &Al[0][wg * 64 + l15][0];
    const unsigned short* rB = &Bl[0][cg * 32 + l15][0];

    const f32x4 fz = {0.f, 0.f, 0.f, 0.f};
    f32x4 acc[8][4];
    #pragma unroll
    for (int i = 0; i < 8; ++i)
        #pragma unroll
        for (int j = 0; j < 4; ++j) acc[i][j] = fz;

    bf16x8 a[4][2], b0[2][2], b1[2][2];

    for (int t = 0; t < KT; ++t) {
        const int bo = (t & 1) << 14;   // current LDS buffer (element offset)
        const int bn = bo ^ 16384;      // next buffer
        const int k1 = (t + 1) << 6;    // global col offset of tile t+1
        const int k2 = (t + 2) << 6;

        // ===== phase 0: A-half0 x B-half0; stage B1(t+1) =====
        // reads in first-consumption order
        a[0][0]  = *(const bf16x8*)&rA[bo + 0 * 1024 + so0];
        b0[0][0] = *(const bf16x8*)&rB[bo + 0 * 1024 + so0];
        a[0][1]  = *(const bf16x8*)&rA[bo + 0 * 1024 + so1];
        b0[0][1] = *(const bf16x8*)&rB[bo + 0 * 1024 + so1];
        b0[1][0] = *(const bf16x8*)&rB[bo + 1 * 1024 + so0];
        b0[1][1] = *(const bf16x8*)&rB[bo + 1 * 1024 + so1];
        a[1][0]  = *(const bf16x8*)&rA[bo + 1 * 1024 + so0];
        a[1][1]  = *(const bf16x8*)&rA[bo + 1 * 1024 + so1];
        a[2][0]  = *(const bf16x8*)&rA[bo + 2 * 1024 + so0];
        a[2][1]  = *(const bf16x8*)&rA[bo + 2 * 1024 + so1];
        a[3][0]  = *(const bf16x8*)&rA[bo + 3 * 1024 + so0];
        a[3][1]  = *(const bf16x8*)&rA[bo + 3 * 1024 + so1];
        if (t + 1 < KT) STG_B(bn, 8192, gB + bH + k1);
        __builtin_amdgcn_s_setprio(1);
        #pragma unroll
        for (int mf = 0; mf < 4; ++mf)
            #pragma unroll
            for (int nf = 0; nf < 2; ++nf) {
                acc[mf][nf] = __builtin_amdgcn_mfma_f32_16x16x32_bf16(a[mf][0], b0[nf][0], acc[mf][nf], 0, 0, 0);
                acc[mf][nf] = __builtin_amdgcn_mfma_f32_16x16x32_bf16(a[mf][1], b0[nf][1], acc[mf][nf], 0, 0, 0);
            }
        __builtin_amdgcn_s_setprio(0);
        __builtin_amdgcn_s_barrier();
        __builtin_amdgcn_sched_barrier(0);

        // ===== phase 1: A-half0 x B-half1; stage A0(t+2) =====
        b1[0][0] = *(const bf16x8*)&rB[bo + 8192 + 0 * 1024 + so0];
        b1[0][1] = *(const bf16x8*)&rB[bo + 8192 + 0 * 1024 + so1];
        b1[1][0] = *(const bf16x8*)&rB[bo + 8192 + 1 * 1024 + so0];
        b1[1][1] = *(const bf16x8*)&rB[bo + 8192 + 1 * 1024 + so1];
        if (t + 2 < KT) STG_A(bo, 0, gA + k2);
        __builtin_amdgcn_s_setprio(1);
        #pragma unroll
        for (int mf = 0; mf < 4; ++mf)
            #pragma unroll
            for (int nf = 0; nf < 2; ++nf) {
                acc[mf][2 + nf] = __builtin_amdgcn_mfma_f32_16x16x32_bf16(a[mf][0], b1[nf][0], acc[mf][2 + nf], 0, 0, 0);
                acc[mf][2 + nf] = __builtin_amdgcn_mfma_f32_16x16x32_bf16(a[mf][1], b1[nf][1], acc[mf][2 + nf], 0, 0, 0);
            }
        __builtin_amdgcn_s_setprio(0);
        __builtin_amdgcn_s_barrier();
        __builtin_amdgcn_sched_barrier(0);

        // ===== phase 2: A-half1 x B-half0; stage B0(t+2) =====
        a[0][0] = *(const bf16x8*)&rA[bo + 8192 + 0 * 1024 + so0];
        a[0][1] = *(const bf16x8*)&rA[bo + 8192 + 0 * 1024 + so1];
        a[1][0] = *(const bf16x8*)&rA[bo + 8192 + 1 * 1024 + so0];
        a[1][1] = *(const bf16x8*)&rA[bo + 8192 + 1 * 1024 + so1];
        a[2][0] = *(const bf16x8*)&rA[bo + 8192 + 2 * 1024 + so0];
        a[2][1] = *(const bf16x8*)&rA[bo + 8192 + 2 * 1024 + so1];
        a[3][0] = *(const bf16x8*)&rA[bo + 8192 + 3 * 1024 + so0];
        a[3][1] = *(const bf16x8*)&rA[bo + 8192 + 3 * 1024 + so1];
        if (t + 2 < KT) STG_B(bo, 0, gB + k2);
        __builtin_amdgcn_s_setprio(1);
        #pragma unroll
        for (int mf = 0; mf < 4; ++mf)
            #pragma unroll
            for (int nf = 0; nf < 2; ++nf) {
                acc[4 + mf][nf] = __builtin_amdgcn_mfma_f32_16x16x32_bf16(a[mf][0], b0[nf][0], acc[4 + mf][nf], 0, 0, 0);
                acc[4 + mf][nf] = __builtin_amdgcn_mfma_f32_16x16x32_bf16(a[mf][1], b0[nf][1], acc[4 + mf][nf], 0, 0, 0);
            }
        __builtin_amdgcn_s_setprio(0);
        __builtin_amdgcn_s_barrier();
        __builtin_amdgcn_sched_barrier(0);

        // ===== phase 3: A-half1 x B-half1 (regs reused); stage A1(t+2) =====
        if (t + 2 < KT) STG_A(bo, 8192, gA + aH + k2);
        __builtin_amdgcn_s_setprio(1);
        #pragma unroll
        for (int mf = 0; mf < 4; ++mf)
            #pragma unroll
            for (int nf = 0; nf < 2; ++nf) {
                acc[4 + mf][2 + nf] = __builtin_amdgcn_mfma_f32_16x16x32_bf16(a[mf][0], b1[nf][0], acc[4 + mf][2 + nf], 0, 0, 0);
                acc[4 + mf][2 + nf] = __builtin_amdgcn_mfma_f32_16x16x32_bf16(a[mf][1], b1[nf][1], acc[4 + mf][2 + nf], 0, 0, 0);
            }
        __builtin_amdgcn_s_setprio(0);
        if (t + 2 < KT) {
            asm volatile("s_waitcnt vmcnt(6)" ::: "memory");   // tile t+1 landed
        } else if (t + 2 == KT) {
            asm volatile("s_waitcnt vmcnt(0)" ::: "memory");   // drain for last tile
        }
        if (t + 1 < KT) {
            __builtin_amdgcn_s_barrier();
            __builtin_amdgcn_sched_barrier(0);
        }
    }
#undef STG_A
#undef STG_B

    // ---- epilogue: D element (row q4*4+rr, col l15) per 16x16 subtile ----
    #pragma unroll
    for (int hm = 0; hm < 2; ++hm)
    #pragma unroll
    for (int mf = 0; mf < 4; ++mf)
    #pragma unroll
    for (int hb = 0; hb < 2; ++hb)
    #pragma unroll
    for (int nf = 0; nf < 2; ++nf)
    #pragma unroll
    for (int rr = 0; rr < 4; ++rr) {
        const int m = m0 + hm * 128 + wg * 64 + mf * 16 + q4 * 4 + rr;
        const int n = n0 + hb * 128 + cg * 32 + nf * 16 + l15;
        const size_t off = (size_t)m * N + n;
        float c = acc[hm * 4 + mf][hb * 2 + nf][rr];
        if (EPI == 0) {
            ((unsigned short*)Cout)[off] = f2bf(c);
        } else if (EPI == 1) {
            ((float*)Cout)[off] = c + bias[n] + resid[off];
        } else if (EPI == 2) {
            ((unsigned short*)Cout)[off] = f2bf(fmaxf(c + bias[n], 0.f));
        } else {   // EPI == 4: K-split accumulate
            ((float*)Cout)[off] = c + resid[off];
        }
    }
}

// ---------------- per-position differential attention: 1 wave / token --------
__global__ __launch_bounds__(256) void attn_pos(const unsigned short* __restrict__ qkv,
                                                const float* __restrict__ lq1,
                                                const float* __restrict__ lq2,
                                                const float* __restrict__ lk1,
                                                const float* __restrict__ lk2,
                                                unsigned short* __restrict__ outg)
{
    __shared__ __align__(16) float q2[4][32][36];
    __shared__ __align__(16) float k2[4][32][36];
    __shared__ __align__(16) float v2[4][16][64];
    __shared__ float att2[4][16][17];

    const int tid  = threadIdx.x;
    const int wave = tid >> 6;
    const int lane = tid & 63;
    const int pos  = blockIdx.x * 4 + wave;

    float s1 = 0.f, s2 = 0.f;
    #pragma unroll
    for (int i = 0; i < 32; ++i) {
        s1 += lq1[i] * lk1[i];
        s2 += lq2[i] * lk2[i];
    }
    const float lam = __expf(s1) - __expf(s2) + LAMBDA_INIT_F;

    const unsigned short* qrow = qkv + (size_t)pos * QKVS;
    const unsigned short* krow = qrow + DM;
    const unsigned short* vrow = qrow + 2 * DM;

    unsigned short tq[16], tk[16], tv[16];
    *(uint4*)&tq[0] = *(const uint4*)&qrow[lane * 16];
    *(uint4*)&tq[8] = *(const uint4*)&qrow[lane * 16 + 8];
    *(uint4*)&tk[0] = *(const uint4*)&krow[lane * 16];
    *(uint4*)&tk[8] = *(const uint4*)&krow[lane * 16 + 8];
    *(uint4*)&tv[0] = *(const uint4*)&vrow[lane * 16];
    *(uint4*)&tv[8] = *(const uint4*)&vrow[lane * 16 + 8];

    #pragma unroll
    for (int jj = 0; jj < 16; ++jj) {
        const int c  = lane * 16 + jj;
        const int h  = c >> 6;
        const int d  = (c >> 1) & 31;
        const int qi = c & 1;
        q2[wave][qi * 16 + h][d] = bf2f(tq[jj]) * QSCALE;
        k2[wave][qi * 16 + h][d] = bf2f(tk[jj]);
        v2[wave][c >> 6][c & 63] = bf2f(tv[jj]);
    }
    __syncthreads();

    const int qh = lane & 31, half = lane >> 5;
    float qreg[32];
    #pragma unroll
    for (int d4 = 0; d4 < 32; d4 += 4) {
        const f32x4 t = *(const f32x4*)&q2[wave][qh][d4];
        qreg[d4] = t[0]; qreg[d4+1] = t[1]; qreg[d4+2] = t[2]; qreg[d4+3] = t[3];
    }
    float p[16];
    #pragma unroll
    for (int jj = 0; jj < 16; ++jj) {
        const float* kr = &k2[wave][half * 16 + jj][0];
        float a = 0.f;
        #pragma unroll
        for (int d4 = 0; d4 < 32; d4 += 4) {
            const f32x4 kv = *(const f32x4*)&kr[d4];
            a += qreg[d4]*kv[0] + qreg[d4+1]*kv[1] + qreg[d4+2]*kv[2] + qreg[d4+3]*kv[3];
        }
        p[jj] = a;
    }

    float mx = p[0];
    #pragma unroll
    for (int jj = 1; jj < 16; ++jj) mx = fmaxf(mx, p[jj]);
    mx = fmaxf(mx, __shfl_xor(mx, 32));
    float sum = 0.f;
    #pragma unroll
    for (int jj = 0; jj < 16; ++jj) { p[jj] = __expf(p[jj] - mx); sum += p[jj]; }
    sum += __shfl_xor(sum, 32);
    const float inv = 1.0f / sum;

    if (half == 0 && qh < 16) {
        #pragma unroll
        for (int jj = 0; jj < 16; ++jj) att2[wave][qh][jj] = p[jj] * inv;
    }
    __syncthreads();
    if (half == 1 && qh >= 16) {
        const int a = qh - 16;
        #pragma unroll
        for (int jj = 0; jj < 16; ++jj) att2[wave][a][jj] -= lam * p[jj] * inv;
    }
    __syncthreads();

    const int a   = lane & 15;
    const int ddb = (lane >> 4) * 16;
    float areg[16];
    #pragma unroll
    for (int h = 0; h < 16; ++h) areg[h] = att2[wave][a][h];
    float o[16];
    #pragma unroll
    for (int j = 0; j < 16; ++j) o[j] = 0.f;
    #pragma unroll
    for (int h = 0; h < 16; ++h) {
        #pragma unroll
        for (int j4 = 0; j4 < 16; j4 += 4) {
            const f32x4 vv = *(const f32x4*)&v2[wave][h][ddb + j4];
            o[j4]   += areg[h] * vv[0];
            o[j4+1] += areg[h] * vv[1];
            o[j4+2] += areg[h] * vv[2];
            o[j4+3] += areg[h] * vv[3];
        }
    }

    float ss = 0.f;
    #pragma unroll
    for (int j = 0; j < 16; ++j) ss += o[j] * o[j];
    ss += __shfl_xor(ss, 16);
    ss += __shfl_xor(ss, 32);
    const float scl = rsqrtf(ss * (1.0f / 64.0f) + 1e-5f) * ONE_MINUS_LI;

    unsigned short ob[16];
    #pragma unroll
    for (int j = 0; j < 16; ++j) ob[j] = f2bf(o[j] * scl);
    unsigned short* orow = outg + (size_t)pos * DM + a * 64 + ddb;
    *(uint4*)&orow[0] = *(const uint4*)&ob[0];
    *(uint4*)&orow[8] = *(const uint4*)&ob[8];
}

// ---------------- launcher ----------------
extern "C" void kernel_launch(void* const* d_in, const int* in_sizes, int n_in,
                              void* d_out, int out_size, void* d_ws, size_t ws_size,
                              hipStream_t stream)
{
    const float* x   = (const float*)d_in[0];
    const float* Wq  = (const float*)d_in[1];
    const float* Wk  = (const float*)d_in[2];
    const float* Wv  = (const float*)d_in[3];
    const float* lq1 = (const float*)d_in[4];
    const float* lq2 = (const float*)d_in[5];
    const float* lk1 = (const float*)d_in[6];
    const float* lk2 = (const float*)d_in[7];
    const float* Wo  = (const float*)d_in[8];
    const float* bo  = (const float*)d_in[9];
    const float* g1  = (const float*)d_in[10];
    const float* be1 = (const float*)d_in[11];
    const float* g2  = (const float*)d_in[12];
    const float* be2 = (const float*)d_in[13];
    const float* W1  = (const float*)d_in[14];
    const float* b1  = (const float*)d_in[15];
    const float* W2  = (const float*)d_in[16];
    const float* b2  = (const float*)d_in[17];
    (void)in_sizes; (void)n_in; (void)out_size;

    // workspace map (lifetimes audited):
    //  [0,6)    wqkv bf16          (live whole pass)
    //  [6,8)    wo bf16            (live whole pass)
    //  [8,16)   w1 bf16            (live whole pass)
    //  [16,24)  w2 bf16            (live whole pass)
    //  [24,56)  h = LN1 out bf16   -> dead after QKV gemm
    //           attn out bf16      (over h) -> dead after Wo gemm
    //           h2 = LN2 out bf16  (over attn) -> live through FFN1
    //  [56,152) qkv bf16           -> dead after attn_pos
    //  [56,120) conn f32           (over qkv) -> live through FFN2 chunk 0
    //  [120,..) t  = FFN1 out bf16 (over qkv tail, dead)  -- FF-chunked
    const size_t MB = 1ull << 20;
    char* ws = (char*)d_ws;
    unsigned short* wqkv = (unsigned short*)(ws);
    unsigned short* wo   = (unsigned short*)(ws + 6 * MB);
    unsigned short* w1   = (unsigned short*)(ws + 8 * MB);
    unsigned short* w2   = (unsigned short*)(ws + 16 * MB);
    unsigned short* h    = (unsigned short*)(ws + 24 * MB);
    unsigned short* qkv  = (unsigned short*)(ws + 56 * MB);
    float*          conn = (float*)(ws + 56 * MB);
    unsigned short* attn = h;
    unsigned short* h2   = h;                                 // over attn (dead post-Wo)
    unsigned short* t    = (unsigned short*)(ws + 120 * MB);

    // chunk FFN over the FF dimension so every GEMM keeps >=256 blocks
    int nf = 1;
    while (nf < 16 && 120 * MB + (size_t)MROWS * (FFDIM / nf) * 2 > ws_size) nf <<= 1;
    const int FC = FFDIM / nf;

    const dim3 b256(256), b512(512);

    cvt6_kernel<<<12288, b256, 0, stream>>>(Wq, Wk, Wv, Wo, W1, W2, wqkv, wo, w1, w2);

    ln_kernel<<<MROWS, b256, 0, stream>>>(x, g1, be1, h);

    gemm256<0><<<dim3(QKVS / 256, MROWS / 256), b512, 0, stream>>>(
        h, wqkv, qkv, nullptr, nullptr, MROWS, QKVS, DM, DM);

    attn_pos<<<MROWS / 4, b256, 0, stream>>>(qkv, lq1, lq2, lk1, lk2, attn);

    gemm256<1><<<dim3(DM / 256, MROWS / 256), b512, 0, stream>>>(
        attn, wo, conn, bo, x, MROWS, DM, DM, DM);

    ln_kernel<<<MROWS, b256, 0, stream>>>(conn, g2, be2, h2);

    for (int c = 0; c < nf; ++c) {
        // t[M][FC] = relu(h2 @ W1[c*FC:(c+1)*FC, :]^T + b1[c*FC:])
        gemm256<2><<<dim3(FC / 256, MROWS / 256), b512, 0, stream>>>(
            h2, w1 + (size_t)c * FC * DM, t, b1 + c * FC, nullptr, MROWS, FC, DM, DM);
        // d_out (+)= t @ W2[:, c*FC:(c+1)*FC]^T [+ b2 + conn on first chunk]
        if (c == 0)
            gemm256<1><<<dim3(DM / 256, MROWS / 256), b512, 0, stream>>>(
                t, w2 + (size_t)c * FC, (float*)d_out, b2, conn, MROWS, DM, FC, FFDIM);
        else
            gemm256<4><<<dim3(DM / 256, MROWS / 256), b512, 0, stream>>>(
                t, w2 + (size_t)c * FC, (float*)d_out, nullptr, (const float*)d_out, MROWS, DM, FC, FFDIM);
    }
}